// Round 14
// baseline (666.165 us; speedup 1.0000x reference)
//
#include <hip/hip_runtime.h>
#include <math.h>

typedef float vf4 __attribute__((ext_vector_type(4)));
typedef float vf2 __attribute__((ext_vector_type(2)));

#define B_TOTAL 131072
#define WPB 8
#define BLOCK_T (WPB * 64)

__device__ __forceinline__ float rfl_f(float v) {
    return __int_as_float(__builtin_amdgcn_readfirstlane(__float_as_int(v)));
}

__device__ __forceinline__ float rdl_f(float v, int l) {
    return __int_as_float(__builtin_amdgcn_readlane(__float_as_int(v), l));
}

// physicists' Hermite H_m(t), m in [0,8), selected per-lane
__device__ __forceinline__ float herm_sel(float t, int m) {
    float h0 = 1.0f;
    float h1 = 2.0f * t;
    float r = (m == 0) ? h0 : h1;
#pragma unroll
    for (int d = 2; d < 8; ++d) {
        float hk = 2.0f * t * h1 - (2.0f * (float)(d - 1)) * h0;
        r = (m == d) ? hk : r;
        h0 = h1;
        h1 = hk;
    }
    return r;
}

// 1/sqrt((2^m * m!) * sqrt(pi)) in f64, same op order as host python
__device__ __forceinline__ float norm_of(int m) {
    double f = 1.0;
#pragma unroll
    for (int d = 2; d < 8; ++d) f = (d <= m) ? f * (double)d : f;
    double p2 = (double)(1 << m);
    double sp = sqrt(3.14159265358979323846);
    return (float)(1.0 / sqrt((p2 * f) * sp));
}

__device__ __forceinline__ float sel6f(const float* a, int m) {
    float r = a[0];
    r = (m == 1) ? a[1] : r;
    r = (m == 2) ? a[2] : r;
    r = (m == 3) ? a[3] : r;
    r = (m == 4) ? a[4] : r;
    r = (m == 5) ? a[5] : r;
    return r;
}

__device__ __forceinline__ int sel6i(const int* a, int m) {
    int r = a[0];
    r = (m == 1) ? a[1] : r;
    r = (m == 2) ? a[2] : r;
    r = (m == 3) ? a[3] : r;
    r = (m == 4) ? a[4] : r;
    r = (m == 5) ? a[5] : r;
    return r;
}

// ==================== Kernel A: Phi + bilinear + A-assembly -> ws[b*16+q] ====================
// LDS = Fuu/Fdd only (32KB exact) -> 3-4 blocks/CU. Phi broadcast via v_readlane
// (no LDS round-trip). Fud (raw, 16KB, L1-resident) from global.
extern "C" __global__ void __launch_bounds__(BLOCK_T, 4)
pfaffA(const float* __restrict__ x, const int* __restrict__ spin,
       const float* __restrict__ Fud, const float* __restrict__ Fuu,
       const float* __restrict__ Fdd, float* __restrict__ wsAp)
{
    __shared__ alignas(16) float sFuu[4096];
    __shared__ alignas(16) float sFdd[4096];

    const int tid = threadIdx.x;

    for (int idx = tid; idx < 4096; idx += BLOCK_T) {
        int l = idx >> 6, k = idx & 63;
        int tr = k * 64 + l;
        sFuu[idx] = Fuu[idx] - Fuu[tr];
        sFdd[idx] = Fdd[idx] - Fdd[tr];
    }
    __syncthreads();
    // no block-wide barriers below: waves independent

    const int wid = tid >> 6;
    const int lane = tid & 63;
    const int b = blockIdx.x * WPB + wid;

    float u[6], v[6];
    int sp6[6];
#pragma unroll
    for (int i = 0; i < 6; ++i) {
        u[i] = rfl_f(x[b * 12 + 2 * i]);
        v[i] = rfl_f(x[b * 12 + 2 * i + 1]);
        sp6[i] = __builtin_amdgcn_readfirstlane(spin[b * 6 + i]);
    }

    const int mx = lane >> 3, my = lane & 7;
    const float nx = norm_of(mx), ny = norm_of(my);
    float Phi[6];
#pragma unroll
    for (int i = 0; i < 6; ++i) {
        float t = u[i] * u[i] + v[i] * v[i];
        float g = expf(-0.5f * t);                       // precise libm exp
        float hxn = herm_sel(u[i], mx) * nx;
        float hyn = herm_sel(v[i], my) * ny;
        Phi[i] = (hxn * hyn) * g;
    }

    // packed-f32 bilinear; Fuu/Fdd from LDS, Fud from global (L1-hot),
    // Phi[*][l] broadcast via v_readlane (uniform chunk-local index).
    vf2 auu[3] = {{0.f,0.f},{0.f,0.f},{0.f,0.f}};
    vf2 add2[3] = {{0.f,0.f},{0.f,0.f},{0.f,0.f}};
    vf2 aud[3] = {{0.f,0.f},{0.f,0.f},{0.f,0.f}};
    const float* fxb = Fud + lane;
#pragma unroll 1
    for (int c = 0; c < 4; ++c) {
#pragma unroll
        for (int l2 = 0; l2 < 16; ++l2) {
            const int l = c * 16 + l2;
            float fu = sFuu[l * 64 + lane];
            float fd = sFdd[l * 64 + lane];
            float fx = fxb[l2 * 64];
            vf2 fu2 = {fu, fu}, fd2 = {fd, fd}, fx2 = {fx, fx};
            vf2 p0 = {rdl_f(Phi[0], l), rdl_f(Phi[1], l)};
            vf2 p1 = {rdl_f(Phi[2], l), rdl_f(Phi[3], l)};
            vf2 p2 = {rdl_f(Phi[4], l), rdl_f(Phi[5], l)};
            auu[0] = __builtin_elementwise_fma(p0, fu2, auu[0]);
            auu[1] = __builtin_elementwise_fma(p1, fu2, auu[1]);
            auu[2] = __builtin_elementwise_fma(p2, fu2, auu[2]);
            add2[0] = __builtin_elementwise_fma(p0, fd2, add2[0]);
            add2[1] = __builtin_elementwise_fma(p1, fd2, add2[1]);
            add2[2] = __builtin_elementwise_fma(p2, fd2, add2[2]);
            aud[0] = __builtin_elementwise_fma(p0, fx2, aud[0]);
            aud[1] = __builtin_elementwise_fma(p1, fx2, aud[1]);
            aud[2] = __builtin_elementwise_fma(p2, fx2, aud[2]);
        }
        fxb += 1024;
    }
    float puu[6], pdd[6], pud[6];
#pragma unroll
    for (int c = 0; c < 3; ++c) {
        puu[2 * c] = auu[c][0];  puu[2 * c + 1] = auu[c][1];
        pdd[2 * c] = add2[c][0]; pdd[2 * c + 1] = add2[c][1];
        pud[2 * c] = aud[c][0];  pud[2 * c + 1] = aud[c][1];
    }

    // A[i<j]: spin-selected bilinear forms, butterfly reduce; lane pidx keeps its value
    float myAp = 0.0f;
    {
        int pidx = 0;
#pragma unroll
        for (int i = 0; i < 6; ++i) {
#pragma unroll
            for (int j = i + 1; j < 6; ++j) {
                int si = sp6[i], sj = sp6[j];
                bool du = (si == 1) && (sj == 0);
                float rowv = (si == 0) ? ((sj == 0) ? puu[i] : pud[i])
                                       : ((sj == 1) ? pdd[i] : pud[j]);
                float colv = du ? Phi[i] : Phi[j];
                float prod = rowv * colv;
                prod = du ? -prod : prod;
#pragma unroll
                for (int m = 32; m >= 1; m >>= 1)
                    prod += __shfl_xor(prod, m, 64);
                myAp = (lane == pidx) ? prod : myAp;
                ++pidx;
            }
        }
    }
    if (lane < 15) wsAp[b * 16 + lane] = myAp;
}

// ==================== Kernel B: per-pair MLP + Pfaffian ====================
// thread = one ordered pair (p<30) of one element; 32 threads (half-wave) per element.
extern "C" __global__ void __launch_bounds__(512, 6)
pfaffB(const float* __restrict__ x, const int* __restrict__ spin,
       const float* __restrict__ W1, const float* __restrict__ b1,
       const float* __restrict__ W2, const float* __restrict__ b2,
       const float* __restrict__ W3, const float* __restrict__ b3,
       const float* __restrict__ scale_p, const float* __restrict__ wsAp,
       float* __restrict__ out)
{
    const int tid = threadIdx.x;
    const int half = tid >> 5;
    const int p = tid & 31;
    const int b = blockIdx.x * 16 + half;

    int i = p / 5;
    int r5 = p - i * 5;
    int j = r5 + ((r5 >= i) ? 1 : 0);
    i = min(i, 5);
    j = min(j, 5);

    float xi = x[b * 12 + 2 * i], yi = x[b * 12 + 2 * i + 1];
    float xj = x[b * 12 + 2 * j], yj = x[b * 12 + 2 * j + 1];
    int si = spin[b * 6 + i], sj = spin[b * 6 + j];

    float dx = xi - xj;
    float dy = yi - yj;
    float r2 = dx * dx + dy * dy;
    float same = (si == sj) ? 1.0f : 0.0f;
    vf2 dx2 = {dx, dx}, dy2 = {dy, dy}, r22 = {r2, r2}, sm2 = {same, same};

    // pk-MLP (R9's exact arithmetic); weight addresses wave-uniform -> s_load
    float h1v[32];
#pragma unroll
    for (int h = 0; h < 32; h += 2) {
        vf2 a = *(const vf2*)&b1[h];
        a = __builtin_elementwise_fma(dx2, *(const vf2*)&W1[h], a);
        a = __builtin_elementwise_fma(dy2, *(const vf2*)&W1[32 + h], a);
        a = __builtin_elementwise_fma(r22, *(const vf2*)&W1[64 + h], a);
        a = __builtin_elementwise_fma(sm2, *(const vf2*)&W1[96 + h], a);
#pragma unroll
        for (int s = 0; s < 2; ++s) {
            float av = a[s];
            float e = __expf(-av);
            h1v[h + s] = __fdividef(av, 1.0f + e);   // silu
        }
    }
    float o = b3[0];
    for (int h2 = 0; h2 < 32; h2 += 2) {
        vf2 a0 = *(const vf2*)&b2[h2];
        vf2 a1 = {0.f, 0.f}, a2 = {0.f, 0.f}, a3 = {0.f, 0.f};
#pragma unroll
        for (int l = 0; l < 32; l += 4) {
            vf2 m0 = {h1v[l + 0], h1v[l + 0]};
            vf2 m1 = {h1v[l + 1], h1v[l + 1]};
            vf2 m2 = {h1v[l + 2], h1v[l + 2]};
            vf2 m3 = {h1v[l + 3], h1v[l + 3]};
            a0 = __builtin_elementwise_fma(m0, *(const vf2*)&W2[(l + 0) * 32 + h2], a0);
            a1 = __builtin_elementwise_fma(m1, *(const vf2*)&W2[(l + 1) * 32 + h2], a1);
            a2 = __builtin_elementwise_fma(m2, *(const vf2*)&W2[(l + 2) * 32 + h2], a2);
            a3 = __builtin_elementwise_fma(m3, *(const vf2*)&W2[(l + 3) * 32 + h2], a3);
        }
        vf2 a = (a0 + a1) + (a2 + a3);
#pragma unroll
        for (int s = 0; s < 2; ++s) {
            float av = a[s];
            float e = __expf(-av);
            float sil = __fdividef(av, 1.0f + e);    // silu
            o = fmaf(sil, W3[h2 + s], o);
        }
    }

    // ---- Af assembly at lanes q<15 of each half-wave ----
    const int t = p & 15;
    const unsigned long long TI = 0x0433222111100000ull;
    const unsigned long long TJ = 0x0554543543254321ull;
    int i2 = (int)((TI >> (4 * t)) & 15);
    int j2 = (int)((TJ >> (4 * t)) & 15);
    float o_ij = __shfl(o, i2 * 5 + (j2 - 1), 32);   // ord(i2,j2), j2>i2
    float o_ji = __shfl(o, j2 * 5 + i2, 32);         // ord(j2,i2)
    const float scl = scale_p[0];
    float ApV = wsAp[b * 16 + t];
    float Af = ApV + scl * (o_ij - o_ji);

    // ---- Pfaffian: lane t<15 computes term t, f64 tree-sum across half ----
    const unsigned long long TA = 0x0444333222111000ull;
    const unsigned long long TB = 0x0765865875876BA9ull;
    const unsigned long long TC = 0x09AC9BDABECDECDEull;
    int ia = (int)((TA >> (4 * t)) & 15);
    int ib = (int)((TB >> (4 * t)) & 15);
    int ic = (int)((TC >> (4 * t)) & 15);
    double Afa = (double)__shfl(Af, ia, 32);
    double Afb = (double)__shfl(Af, ib, 32);
    double Afc = (double)__shfl(Af, ic, 32);
    double pd = Afa * Afb * Afc;
    pd = (t & 1) ? -pd : pd;
    pd = (p < 15) ? pd : 0.0;
#pragma unroll
    for (int m = 16; m >= 1; m >>= 1)
        pd += __shfl_xor(pd, m, 32);

    if (p == 0) {
        float pf = (float)pd;
        float sg = (pf == 0.0f) ? 1.0f : ((pf > 0.0f) ? 1.0f : -1.0f);
        float tt = pf * pf;                // ref adds 1e-60 which is 0 in f32
        float la = 0.5f * logf(tt);
        out[b] = sg;
        out[B_TOTAL + b] = la;
    }
}

// ==================== fallback (ws too small): R9 fused kernel ====================
extern "C" __global__ void __launch_bounds__(BLOCK_T, 4)
pfaff6_full(const float* __restrict__ x, const int* __restrict__ spin,
            const float* __restrict__ Fud, const float* __restrict__ Fuu,
            const float* __restrict__ Fdd,
            const float* __restrict__ W1, const float* __restrict__ b1,
            const float* __restrict__ W2, const float* __restrict__ b2,
            const float* __restrict__ W3, const float* __restrict__ b3,
            const float* __restrict__ scale_p,
            float* __restrict__ out)
{
    __shared__ alignas(16) float sFuu[4096];
    __shared__ alignas(16) float sFdd[4096];
    __shared__ alignas(16) float sFud[4096];
    __shared__ alignas(16) float sPhi2[WPB][3][128];
    __shared__ float sOut[WPB][32];

    const int tid = threadIdx.x;
    for (int idx = tid; idx < 4096; idx += BLOCK_T) {
        int l = idx >> 6, k = idx & 63;
        int tr = k * 64 + l;
        sFuu[idx] = Fuu[idx] - Fuu[tr];
        sFdd[idx] = Fdd[idx] - Fdd[tr];
        sFud[idx] = Fud[idx];
    }
    __syncthreads();

    const int wid = tid >> 6;
    const int lane = tid & 63;
    const int b = blockIdx.x * WPB + wid;

    float u[6], v[6];
    int sp6[6];
#pragma unroll
    for (int i = 0; i < 6; ++i) {
        u[i] = rfl_f(x[b * 12 + 2 * i]);
        v[i] = rfl_f(x[b * 12 + 2 * i + 1]);
        sp6[i] = __builtin_amdgcn_readfirstlane(spin[b * 6 + i]);
    }

    const int mx = lane >> 3, my = lane & 7;
    const float nx = norm_of(mx), ny = norm_of(my);
    float Phi[6];
#pragma unroll
    for (int i = 0; i < 6; ++i) {
        float t = u[i] * u[i] + v[i] * v[i];
        float g = expf(-0.5f * t);
        float ph = ((herm_sel(u[i], mx) * nx) * (herm_sel(v[i], my) * ny)) * g;
        Phi[i] = ph;
        sPhi2[wid][i >> 1][lane * 2 + (i & 1)] = ph;
    }
    asm volatile("s_waitcnt lgkmcnt(0)" ::: "memory");
    __builtin_amdgcn_sched_barrier(0);

    vf2 auu[3] = {{0.f,0.f},{0.f,0.f},{0.f,0.f}};
    vf2 add2[3] = {{0.f,0.f},{0.f,0.f},{0.f,0.f}};
    vf2 aud[3] = {{0.f,0.f},{0.f,0.f},{0.f,0.f}};
    for (int l2 = 0; l2 < 64; l2 += 2) {
        vf4 pq0 = *(const vf4*)&sPhi2[wid][0][l2 * 2];
        vf4 pq1 = *(const vf4*)&sPhi2[wid][1][l2 * 2];
        vf4 pq2 = *(const vf4*)&sPhi2[wid][2][l2 * 2];
#pragma unroll
        for (int d = 0; d < 2; ++d) {
            int l = l2 + d;
            float fu = sFuu[l * 64 + lane];
            float fd = sFdd[l * 64 + lane];
            float fx = sFud[l * 64 + lane];
            vf2 fu2 = {fu, fu}, fd2 = {fd, fd}, fx2 = {fx, fx};
            vf2 p0 = {pq0[2 * d], pq0[2 * d + 1]};
            vf2 p1 = {pq1[2 * d], pq1[2 * d + 1]};
            vf2 p2 = {pq2[2 * d], pq2[2 * d + 1]};
            auu[0] = __builtin_elementwise_fma(p0, fu2, auu[0]);
            auu[1] = __builtin_elementwise_fma(p1, fu2, auu[1]);
            auu[2] = __builtin_elementwise_fma(p2, fu2, auu[2]);
            add2[0] = __builtin_elementwise_fma(p0, fd2, add2[0]);
            add2[1] = __builtin_elementwise_fma(p1, fd2, add2[1]);
            add2[2] = __builtin_elementwise_fma(p2, fd2, add2[2]);
            aud[0] = __builtin_elementwise_fma(p0, fx2, aud[0]);
            aud[1] = __builtin_elementwise_fma(p1, fx2, aud[1]);
            aud[2] = __builtin_elementwise_fma(p2, fx2, aud[2]);
        }
    }
    float puu[6], pdd[6], pud[6];
#pragma unroll
    for (int c = 0; c < 3; ++c) {
        puu[2 * c] = auu[c][0];  puu[2 * c + 1] = auu[c][1];
        pdd[2 * c] = add2[c][0]; pdd[2 * c + 1] = add2[c][1];
        pud[2 * c] = aud[c][0];  pud[2 * c + 1] = aud[c][1];
    }

    float Ap[15];
    {
        int pidx = 0;
#pragma unroll
        for (int i = 0; i < 6; ++i) {
#pragma unroll
            for (int j = i + 1; j < 6; ++j) {
                int si = sp6[i], sj = sp6[j];
                bool du = (si == 1) && (sj == 0);
                float rowv = (si == 0) ? ((sj == 0) ? puu[i] : pud[i])
                                       : ((sj == 1) ? pdd[i] : pud[j]);
                float colv = du ? Phi[i] : Phi[j];
                float prod = rowv * colv;
                prod = du ? -prod : prod;
#pragma unroll
                for (int m = 32; m >= 1; m >>= 1)
                    prod += __shfl_xor(prod, m, 64);
                Ap[pidx++] = rfl_f(prod);
            }
        }
    }

    {
        int p = lane;
        int i = p / 5;
        int r5 = p - i * 5;
        int j = r5 + ((r5 >= i) ? 1 : 0);
        i = min(i, 5);
        j = min(j, 5);
        float dx = sel6f(u, i) - sel6f(u, j);
        float dy = sel6f(v, i) - sel6f(v, j);
        float r2 = dx * dx + dy * dy;
        float same = (sel6i(sp6, i) == sel6i(sp6, j)) ? 1.0f : 0.0f;
        vf2 dx2 = {dx, dx}, dy2 = {dy, dy}, r22 = {r2, r2}, sm2 = {same, same};

        float h1v[32];
#pragma unroll
        for (int h = 0; h < 32; h += 2) {
            vf2 a = *(const vf2*)&b1[h];
            a = __builtin_elementwise_fma(dx2, *(const vf2*)&W1[h], a);
            a = __builtin_elementwise_fma(dy2, *(const vf2*)&W1[32 + h], a);
            a = __builtin_elementwise_fma(r22, *(const vf2*)&W1[64 + h], a);
            a = __builtin_elementwise_fma(sm2, *(const vf2*)&W1[96 + h], a);
#pragma unroll
            for (int s = 0; s < 2; ++s) {
                float av = a[s];
                float e = __expf(-av);
                h1v[h + s] = __fdividef(av, 1.0f + e);
            }
        }
        float o = b3[0];
        for (int h2 = 0; h2 < 32; h2 += 2) {
            vf2 a0 = *(const vf2*)&b2[h2];
            vf2 a1 = {0.f, 0.f}, a2 = {0.f, 0.f}, a3 = {0.f, 0.f};
#pragma unroll
            for (int l = 0; l < 32; l += 4) {
                vf2 m0 = {h1v[l + 0], h1v[l + 0]};
                vf2 m1 = {h1v[l + 1], h1v[l + 1]};
                vf2 m2 = {h1v[l + 2], h1v[l + 2]};
                vf2 m3 = {h1v[l + 3], h1v[l + 3]};
                a0 = __builtin_elementwise_fma(m0, *(const vf2*)&W2[(l + 0) * 32 + h2], a0);
                a1 = __builtin_elementwise_fma(m1, *(const vf2*)&W2[(l + 1) * 32 + h2], a1);
                a2 = __builtin_elementwise_fma(m2, *(const vf2*)&W2[(l + 2) * 32 + h2], a2);
                a3 = __builtin_elementwise_fma(m3, *(const vf2*)&W2[(l + 3) * 32 + h2], a3);
            }
            vf2 a = (a0 + a1) + (a2 + a3);
#pragma unroll
            for (int s = 0; s < 2; ++s) {
                float av = a[s];
                float e = __expf(-av);
                float sil = __fdividef(av, 1.0f + e);
                o = fmaf(sil, W3[h2 + s], o);
            }
        }
        if (p < 30) sOut[wid][p] = o;
    }
    asm volatile("s_waitcnt lgkmcnt(0)" ::: "memory");
    __builtin_amdgcn_sched_barrier(0);

    const float scl = rfl_f(scale_p[0]);
    float Af[15];
    {
        int pidx = 0;
#pragma unroll
        for (int i = 0; i < 6; ++i) {
#pragma unroll
            for (int j = i + 1; j < 6; ++j) {
                float o_ij = sOut[wid][i * 5 + (j - 1)];
                float o_ji = sOut[wid][j * 5 + i];
                Af[pidx] = Ap[pidx] + scl * (o_ij - o_ji);
                ++pidx;
            }
        }
    }
    {
        double pfd = 0.0;
#define PFT(sgn, a, bb, c) pfd += (sgn) * ((double)Af[a] * (double)Af[bb] * (double)Af[c]);
        PFT( 1.0, 0, 9, 14) PFT(-1.0, 0, 10, 13) PFT( 1.0, 0, 11, 12)
        PFT(-1.0, 1, 6, 14) PFT( 1.0, 1, 7, 13)  PFT(-1.0, 1, 8, 12)
        PFT( 1.0, 2, 5, 14) PFT(-1.0, 2, 7, 11)  PFT( 1.0, 2, 8, 10)
        PFT(-1.0, 3, 5, 13) PFT( 1.0, 3, 6, 11)  PFT(-1.0, 3, 8, 9)
        PFT( 1.0, 4, 5, 12) PFT(-1.0, 4, 6, 10)  PFT( 1.0, 4, 7, 9)
#undef PFT
        if (lane == 0) {
            float pf = (float)pfd;
            float sg = (pf == 0.0f) ? 1.0f : ((pf > 0.0f) ? 1.0f : -1.0f);
            float t = pf * pf;
            float la = 0.5f * logf(t);
            out[b] = sg;
            out[B_TOTAL + b] = la;
        }
    }
}

extern "C" void kernel_launch(void* const* d_in, const int* in_sizes, int n_in,
                              void* d_out, int out_size, void* d_ws, size_t ws_size,
                              hipStream_t stream) {
    const float* x     = (const float*)d_in[0];
    const int*   spin  = (const int*)d_in[1];
    const float* Fud   = (const float*)d_in[2];
    const float* Fuu   = (const float*)d_in[3];
    const float* Fdd   = (const float*)d_in[4];
    const float* W1    = (const float*)d_in[5];
    const float* b1    = (const float*)d_in[6];
    const float* W2    = (const float*)d_in[7];
    const float* b2    = (const float*)d_in[8];
    const float* W3    = (const float*)d_in[9];
    const float* b3    = (const float*)d_in[10];
    const float* scale = (const float*)d_in[11];
    float* out = (float*)d_out;

    const size_t wsNeed = (size_t)B_TOTAL * 16 * sizeof(float);
    if (ws_size >= wsNeed) {
        float* wsAp = (float*)d_ws;
        hipLaunchKernelGGL(pfaffA, dim3(B_TOTAL / WPB), dim3(BLOCK_T), 0, stream,
                           x, spin, Fud, Fuu, Fdd, wsAp);
        hipLaunchKernelGGL(pfaffB, dim3(B_TOTAL / 16), dim3(512), 0, stream,
                           x, spin, W1, b1, W2, b2, W3, b3, scale, wsAp, out);
    } else {
        hipLaunchKernelGGL(pfaff6_full, dim3(B_TOTAL / WPB), dim3(BLOCK_T), 0, stream,
                           x, spin, Fud, Fuu, Fdd, W1, b1, W2, b2, W3, b3, scale, out);
    }
}

// Round 15
// 643.899 us; speedup vs baseline: 1.0346x; 1.0346x over previous
//
#include <hip/hip_runtime.h>
#include <math.h>

typedef float vf4 __attribute__((ext_vector_type(4)));
typedef float vf2 __attribute__((ext_vector_type(2)));

#define B_TOTAL 131072
#define WPB 8
#define BLOCK_T (WPB * 64)

__device__ __forceinline__ float rfl_f(float v) {
    return __int_as_float(__builtin_amdgcn_readfirstlane(__float_as_int(v)));
}

// physicists' Hermite H_m(t), m in [0,8), selected per-lane
__device__ __forceinline__ float herm_sel(float t, int m) {
    float h0 = 1.0f;
    float h1 = 2.0f * t;
    float r = (m == 0) ? h0 : h1;
#pragma unroll
    for (int d = 2; d < 8; ++d) {
        float hk = 2.0f * t * h1 - (2.0f * (float)(d - 1)) * h0;
        r = (m == d) ? hk : r;
        h0 = h1;
        h1 = hk;
    }
    return r;
}

// 1/sqrt((2^m * m!) * sqrt(pi)) in f64, same op order as host python
__device__ __forceinline__ float norm_of(int m) {
    double f = 1.0;
#pragma unroll
    for (int d = 2; d < 8; ++d) f = (d <= m) ? f * (double)d : f;
    double p2 = (double)(1 << m);
    double sp = sqrt(3.14159265358979323846);
    return (float)(1.0 / sqrt((p2 * f) * sp));
}

__device__ __forceinline__ float sel6f(const float* a, int m) {
    float r = a[0];
    r = (m == 1) ? a[1] : r;
    r = (m == 2) ? a[2] : r;
    r = (m == 3) ? a[3] : r;
    r = (m == 4) ? a[4] : r;
    r = (m == 5) ? a[5] : r;
    return r;
}

__device__ __forceinline__ int sel6i(const int* a, int m) {
    int r = a[0];
    r = (m == 1) ? a[1] : r;
    r = (m == 2) ? a[2] : r;
    r = (m == 3) ? a[3] : r;
    r = (m == 4) ? a[4] : r;
    r = (m == 5) ? a[5] : r;
    return r;
}

// ==================== Kernel A: Phi + bilinear + A-assembly -> ws[b*16+q] ====================
// LDS = Fuu/Fdd (32KB) + chunked Phi stage (3KB) = 35.8KB -> 3 blocks/CU.
// Phi broadcast via ds_read_b128 of a per-chunk wave-local buffer (R12's fast
// form, bit-identical Ap); Fud (raw, 16KB, L1-resident) from global.
extern "C" __global__ void __launch_bounds__(BLOCK_T, 4)
pfaffA(const float* __restrict__ x, const int* __restrict__ spin,
       const float* __restrict__ Fud, const float* __restrict__ Fuu,
       const float* __restrict__ Fdd, float* __restrict__ wsAp)
{
    __shared__ alignas(16) float sFuu[4096];
    __shared__ alignas(16) float sFdd[4096];
    // per-chunk pair-interleaved Phi: sPhiC[w][ch][cl*2+h] = Phi[2ch+h] of l=16c+cl
    __shared__ alignas(16) float sPhiC[WPB][3][32];

    const int tid = threadIdx.x;

    for (int idx = tid; idx < 4096; idx += BLOCK_T) {
        int l = idx >> 6, k = idx & 63;
        int tr = k * 64 + l;
        sFuu[idx] = Fuu[idx] - Fuu[tr];
        sFdd[idx] = Fdd[idx] - Fdd[tr];
    }
    __syncthreads();
    // no block-wide barriers below: waves independent

    const int wid = tid >> 6;
    const int lane = tid & 63;
    const int b = blockIdx.x * WPB + wid;

    float u[6], v[6];
    int sp6[6];
#pragma unroll
    for (int i = 0; i < 6; ++i) {
        u[i] = rfl_f(x[b * 12 + 2 * i]);
        v[i] = rfl_f(x[b * 12 + 2 * i + 1]);
        sp6[i] = __builtin_amdgcn_readfirstlane(spin[b * 6 + i]);
    }

    const int mx = lane >> 3, my = lane & 7;
    const float nx = norm_of(mx), ny = norm_of(my);
    float Phi[6];
#pragma unroll
    for (int i = 0; i < 6; ++i) {
        float t = u[i] * u[i] + v[i] * v[i];
        float g = expf(-0.5f * t);                       // precise libm exp
        float hxn = herm_sel(u[i], mx) * nx;
        float hyn = herm_sel(v[i], my) * ny;
        Phi[i] = (hxn * hyn) * g;
    }

    // packed-f32 bilinear; Fuu/Fdd from LDS, Fud from global (L1-hot),
    // Phi broadcast via per-chunk LDS stage + ds_read_b128.
    vf2 auu[3] = {{0.f,0.f},{0.f,0.f},{0.f,0.f}};
    vf2 add2[3] = {{0.f,0.f},{0.f,0.f},{0.f,0.f}};
    vf2 aud[3] = {{0.f,0.f},{0.f,0.f},{0.f,0.f}};
    const float* fxb = Fud + lane;
    const int cl = lane & 15;
#pragma unroll 1
    for (int c = 0; c < 4; ++c) {
        // stage Phi for l in [16c, 16c+16): lanes of this chunk write theirs.
        // (DS pipe is in-order per wave; waits fence compiler + HW ordering)
        asm volatile("s_waitcnt lgkmcnt(0)" ::: "memory");
        __builtin_amdgcn_sched_barrier(0);
        if ((lane >> 4) == c) {
#pragma unroll
            for (int i = 0; i < 6; ++i)
                sPhiC[wid][i >> 1][cl * 2 + (i & 1)] = Phi[i];
        }
        asm volatile("s_waitcnt lgkmcnt(0)" ::: "memory");
        __builtin_amdgcn_sched_barrier(0);

#pragma unroll
        for (int l2 = 0; l2 < 16; l2 += 2) {
            const int l = c * 16 + l2;
            vf4 pq0 = *(const vf4*)&sPhiC[wid][0][l2 * 2];
            vf4 pq1 = *(const vf4*)&sPhiC[wid][1][l2 * 2];
            vf4 pq2 = *(const vf4*)&sPhiC[wid][2][l2 * 2];
#pragma unroll
            for (int d = 0; d < 2; ++d) {
                float fu = sFuu[(l + d) * 64 + lane];
                float fd = sFdd[(l + d) * 64 + lane];
                float fx = fxb[(l2 + d) * 64];
                vf2 fu2 = {fu, fu}, fd2 = {fd, fd}, fx2 = {fx, fx};
                vf2 p0 = {pq0[2 * d], pq0[2 * d + 1]};
                vf2 p1 = {pq1[2 * d], pq1[2 * d + 1]};
                vf2 p2 = {pq2[2 * d], pq2[2 * d + 1]};
                auu[0] = __builtin_elementwise_fma(p0, fu2, auu[0]);
                auu[1] = __builtin_elementwise_fma(p1, fu2, auu[1]);
                auu[2] = __builtin_elementwise_fma(p2, fu2, auu[2]);
                add2[0] = __builtin_elementwise_fma(p0, fd2, add2[0]);
                add2[1] = __builtin_elementwise_fma(p1, fd2, add2[1]);
                add2[2] = __builtin_elementwise_fma(p2, fd2, add2[2]);
                aud[0] = __builtin_elementwise_fma(p0, fx2, aud[0]);
                aud[1] = __builtin_elementwise_fma(p1, fx2, aud[1]);
                aud[2] = __builtin_elementwise_fma(p2, fx2, aud[2]);
            }
        }
        fxb += 1024;
    }
    float puu[6], pdd[6], pud[6];
#pragma unroll
    for (int c = 0; c < 3; ++c) {
        puu[2 * c] = auu[c][0];  puu[2 * c + 1] = auu[c][1];
        pdd[2 * c] = add2[c][0]; pdd[2 * c + 1] = add2[c][1];
        pud[2 * c] = aud[c][0];  pud[2 * c + 1] = aud[c][1];
    }

    // A[i<j]: spin-selected bilinear forms, butterfly reduce; lane pidx keeps its value
    float myAp = 0.0f;
    {
        int pidx = 0;
#pragma unroll
        for (int i = 0; i < 6; ++i) {
#pragma unroll
            for (int j = i + 1; j < 6; ++j) {
                int si = sp6[i], sj = sp6[j];
                bool du = (si == 1) && (sj == 0);
                float rowv = (si == 0) ? ((sj == 0) ? puu[i] : pud[i])
                                       : ((sj == 1) ? pdd[i] : pud[j]);
                float colv = du ? Phi[i] : Phi[j];
                float prod = rowv * colv;
                prod = du ? -prod : prod;
#pragma unroll
                for (int m = 32; m >= 1; m >>= 1)
                    prod += __shfl_xor(prod, m, 64);
                myAp = (lane == pidx) ? prod : myAp;
                ++pidx;
            }
        }
    }
    if (lane < 15) wsAp[b * 16 + lane] = myAp;
}

// ==================== Kernel B: per-pair MLP + Pfaffian ====================
// thread = one ordered pair (p<30) of one element; 32 threads (half-wave) per element.
extern "C" __global__ void __launch_bounds__(512, 6)
pfaffB(const float* __restrict__ x, const int* __restrict__ spin,
       const float* __restrict__ W1, const float* __restrict__ b1,
       const float* __restrict__ W2, const float* __restrict__ b2,
       const float* __restrict__ W3, const float* __restrict__ b3,
       const float* __restrict__ scale_p, const float* __restrict__ wsAp,
       float* __restrict__ out)
{
    const int tid = threadIdx.x;
    const int half = tid >> 5;
    const int p = tid & 31;
    const int b = blockIdx.x * 16 + half;

    int i = p / 5;
    int r5 = p - i * 5;
    int j = r5 + ((r5 >= i) ? 1 : 0);
    i = min(i, 5);
    j = min(j, 5);

    float xi = x[b * 12 + 2 * i], yi = x[b * 12 + 2 * i + 1];
    float xj = x[b * 12 + 2 * j], yj = x[b * 12 + 2 * j + 1];
    int si = spin[b * 6 + i], sj = spin[b * 6 + j];

    float dx = xi - xj;
    float dy = yi - yj;
    float r2 = dx * dx + dy * dy;
    float same = (si == sj) ? 1.0f : 0.0f;
    vf2 dx2 = {dx, dx}, dy2 = {dy, dy}, r22 = {r2, r2}, sm2 = {same, same};

    // pk-MLP (R9's exact arithmetic); weight addresses wave-uniform -> s_load
    float h1v[32];
#pragma unroll
    for (int h = 0; h < 32; h += 2) {
        vf2 a = *(const vf2*)&b1[h];
        a = __builtin_elementwise_fma(dx2, *(const vf2*)&W1[h], a);
        a = __builtin_elementwise_fma(dy2, *(const vf2*)&W1[32 + h], a);
        a = __builtin_elementwise_fma(r22, *(const vf2*)&W1[64 + h], a);
        a = __builtin_elementwise_fma(sm2, *(const vf2*)&W1[96 + h], a);
#pragma unroll
        for (int s = 0; s < 2; ++s) {
            float av = a[s];
            float e = __expf(-av);
            h1v[h + s] = __fdividef(av, 1.0f + e);   // silu
        }
    }
    float o = b3[0];
    for (int h2 = 0; h2 < 32; h2 += 2) {
        vf2 a0 = *(const vf2*)&b2[h2];
        vf2 a1 = {0.f, 0.f}, a2 = {0.f, 0.f}, a3 = {0.f, 0.f};
#pragma unroll
        for (int l = 0; l < 32; l += 4) {
            vf2 m0 = {h1v[l + 0], h1v[l + 0]};
            vf2 m1 = {h1v[l + 1], h1v[l + 1]};
            vf2 m2 = {h1v[l + 2], h1v[l + 2]};
            vf2 m3 = {h1v[l + 3], h1v[l + 3]};
            a0 = __builtin_elementwise_fma(m0, *(const vf2*)&W2[(l + 0) * 32 + h2], a0);
            a1 = __builtin_elementwise_fma(m1, *(const vf2*)&W2[(l + 1) * 32 + h2], a1);
            a2 = __builtin_elementwise_fma(m2, *(const vf2*)&W2[(l + 2) * 32 + h2], a2);
            a3 = __builtin_elementwise_fma(m3, *(const vf2*)&W2[(l + 3) * 32 + h2], a3);
        }
        vf2 a = (a0 + a1) + (a2 + a3);
#pragma unroll
        for (int s = 0; s < 2; ++s) {
            float av = a[s];
            float e = __expf(-av);
            float sil = __fdividef(av, 1.0f + e);    // silu
            o = fmaf(sil, W3[h2 + s], o);
        }
    }

    // ---- Af assembly at lanes q<15 of each half-wave ----
    const int t = p & 15;
    const unsigned long long TI = 0x0433222111100000ull;
    const unsigned long long TJ = 0x0554543543254321ull;
    int i2 = (int)((TI >> (4 * t)) & 15);
    int j2 = (int)((TJ >> (4 * t)) & 15);
    float o_ij = __shfl(o, i2 * 5 + (j2 - 1), 32);   // ord(i2,j2), j2>i2
    float o_ji = __shfl(o, j2 * 5 + i2, 32);         // ord(j2,i2)
    const float scl = scale_p[0];
    float ApV = wsAp[b * 16 + t];
    float Af = ApV + scl * (o_ij - o_ji);

    // ---- Pfaffian: lane t<15 computes term t, f64 tree-sum across half ----
    const unsigned long long TA = 0x0444333222111000ull;
    const unsigned long long TB = 0x0765865875876BA9ull;
    const unsigned long long TC = 0x09AC9BDABECDECDEull;
    int ia = (int)((TA >> (4 * t)) & 15);
    int ib = (int)((TB >> (4 * t)) & 15);
    int ic = (int)((TC >> (4 * t)) & 15);
    double Afa = (double)__shfl(Af, ia, 32);
    double Afb = (double)__shfl(Af, ib, 32);
    double Afc = (double)__shfl(Af, ic, 32);
    double pd = Afa * Afb * Afc;
    pd = (t & 1) ? -pd : pd;
    pd = (p < 15) ? pd : 0.0;
#pragma unroll
    for (int m = 16; m >= 1; m >>= 1)
        pd += __shfl_xor(pd, m, 32);

    if (p == 0) {
        float pf = (float)pd;
        float sg = (pf == 0.0f) ? 1.0f : ((pf > 0.0f) ? 1.0f : -1.0f);
        float tt = pf * pf;                // ref adds 1e-60 which is 0 in f32
        float la = 0.5f * logf(tt);
        out[b] = sg;
        out[B_TOTAL + b] = la;
    }
}

// ==================== fallback (ws too small): R9 fused kernel ====================
extern "C" __global__ void __launch_bounds__(BLOCK_T, 4)
pfaff6_full(const float* __restrict__ x, const int* __restrict__ spin,
            const float* __restrict__ Fud, const float* __restrict__ Fuu,
            const float* __restrict__ Fdd,
            const float* __restrict__ W1, const float* __restrict__ b1,
            const float* __restrict__ W2, const float* __restrict__ b2,
            const float* __restrict__ W3, const float* __restrict__ b3,
            const float* __restrict__ scale_p,
            float* __restrict__ out)
{
    __shared__ alignas(16) float sFuu[4096];
    __shared__ alignas(16) float sFdd[4096];
    __shared__ alignas(16) float sFud[4096];
    __shared__ alignas(16) float sPhi2[WPB][3][128];
    __shared__ float sOut[WPB][32];

    const int tid = threadIdx.x;
    for (int idx = tid; idx < 4096; idx += BLOCK_T) {
        int l = idx >> 6, k = idx & 63;
        int tr = k * 64 + l;
        sFuu[idx] = Fuu[idx] - Fuu[tr];
        sFdd[idx] = Fdd[idx] - Fdd[tr];
        sFud[idx] = Fud[idx];
    }
    __syncthreads();

    const int wid = tid >> 6;
    const int lane = tid & 63;
    const int b = blockIdx.x * WPB + wid;

    float u[6], v[6];
    int sp6[6];
#pragma unroll
    for (int i = 0; i < 6; ++i) {
        u[i] = rfl_f(x[b * 12 + 2 * i]);
        v[i] = rfl_f(x[b * 12 + 2 * i + 1]);
        sp6[i] = __builtin_amdgcn_readfirstlane(spin[b * 6 + i]);
    }

    const int mx = lane >> 3, my = lane & 7;
    const float nx = norm_of(mx), ny = norm_of(my);
    float Phi[6];
#pragma unroll
    for (int i = 0; i < 6; ++i) {
        float t = u[i] * u[i] + v[i] * v[i];
        float g = expf(-0.5f * t);
        float ph = ((herm_sel(u[i], mx) * nx) * (herm_sel(v[i], my) * ny)) * g;
        Phi[i] = ph;
        sPhi2[wid][i >> 1][lane * 2 + (i & 1)] = ph;
    }
    asm volatile("s_waitcnt lgkmcnt(0)" ::: "memory");
    __builtin_amdgcn_sched_barrier(0);

    vf2 auu[3] = {{0.f,0.f},{0.f,0.f},{0.f,0.f}};
    vf2 add2[3] = {{0.f,0.f},{0.f,0.f},{0.f,0.f}};
    vf2 aud[3] = {{0.f,0.f},{0.f,0.f},{0.f,0.f}};
    for (int l2 = 0; l2 < 64; l2 += 2) {
        vf4 pq0 = *(const vf4*)&sPhi2[wid][0][l2 * 2];
        vf4 pq1 = *(const vf4*)&sPhi2[wid][1][l2 * 2];
        vf4 pq2 = *(const vf4*)&sPhi2[wid][2][l2 * 2];
#pragma unroll
        for (int d = 0; d < 2; ++d) {
            int l = l2 + d;
            float fu = sFuu[l * 64 + lane];
            float fd = sFdd[l * 64 + lane];
            float fx = sFud[l * 64 + lane];
            vf2 fu2 = {fu, fu}, fd2 = {fd, fd}, fx2 = {fx, fx};
            vf2 p0 = {pq0[2 * d], pq0[2 * d + 1]};
            vf2 p1 = {pq1[2 * d], pq1[2 * d + 1]};
            vf2 p2 = {pq2[2 * d], pq2[2 * d + 1]};
            auu[0] = __builtin_elementwise_fma(p0, fu2, auu[0]);
            auu[1] = __builtin_elementwise_fma(p1, fu2, auu[1]);
            auu[2] = __builtin_elementwise_fma(p2, fu2, auu[2]);
            add2[0] = __builtin_elementwise_fma(p0, fd2, add2[0]);
            add2[1] = __builtin_elementwise_fma(p1, fd2, add2[1]);
            add2[2] = __builtin_elementwise_fma(p2, fd2, add2[2]);
            aud[0] = __builtin_elementwise_fma(p0, fx2, aud[0]);
            aud[1] = __builtin_elementwise_fma(p1, fx2, aud[1]);
            aud[2] = __builtin_elementwise_fma(p2, fx2, aud[2]);
        }
    }
    float puu[6], pdd[6], pud[6];
#pragma unroll
    for (int c = 0; c < 3; ++c) {
        puu[2 * c] = auu[c][0];  puu[2 * c + 1] = auu[c][1];
        pdd[2 * c] = add2[c][0]; pdd[2 * c + 1] = add2[c][1];
        pud[2 * c] = aud[c][0];  pud[2 * c + 1] = aud[c][1];
    }

    float Ap[15];
    {
        int pidx = 0;
#pragma unroll
        for (int i = 0; i < 6; ++i) {
#pragma unroll
            for (int j = i + 1; j < 6; ++j) {
                int si = sp6[i], sj = sp6[j];
                bool du = (si == 1) && (sj == 0);
                float rowv = (si == 0) ? ((sj == 0) ? puu[i] : pud[i])
                                       : ((sj == 1) ? pdd[i] : pud[j]);
                float colv = du ? Phi[i] : Phi[j];
                float prod = rowv * colv;
                prod = du ? -prod : prod;
#pragma unroll
                for (int m = 32; m >= 1; m >>= 1)
                    prod += __shfl_xor(prod, m, 64);
                Ap[pidx++] = rfl_f(prod);
            }
        }
    }

    {
        int p = lane;
        int i = p / 5;
        int r5 = p - i * 5;
        int j = r5 + ((r5 >= i) ? 1 : 0);
        i = min(i, 5);
        j = min(j, 5);
        float dx = sel6f(u, i) - sel6f(u, j);
        float dy = sel6f(v, i) - sel6f(v, j);
        float r2 = dx * dx + dy * dy;
        float same = (sel6i(sp6, i) == sel6i(sp6, j)) ? 1.0f : 0.0f;
        vf2 dx2 = {dx, dx}, dy2 = {dy, dy}, r22 = {r2, r2}, sm2 = {same, same};

        float h1v[32];
#pragma unroll
        for (int h = 0; h < 32; h += 2) {
            vf2 a = *(const vf2*)&b1[h];
            a = __builtin_elementwise_fma(dx2, *(const vf2*)&W1[h], a);
            a = __builtin_elementwise_fma(dy2, *(const vf2*)&W1[32 + h], a);
            a = __builtin_elementwise_fma(r22, *(const vf2*)&W1[64 + h], a);
            a = __builtin_elementwise_fma(sm2, *(const vf2*)&W1[96 + h], a);
#pragma unroll
            for (int s = 0; s < 2; ++s) {
                float av = a[s];
                float e = __expf(-av);
                h1v[h + s] = __fdividef(av, 1.0f + e);
            }
        }
        float o = b3[0];
        for (int h2 = 0; h2 < 32; h2 += 2) {
            vf2 a0 = *(const vf2*)&b2[h2];
            vf2 a1 = {0.f, 0.f}, a2 = {0.f, 0.f}, a3 = {0.f, 0.f};
#pragma unroll
            for (int l = 0; l < 32; l += 4) {
                vf2 m0 = {h1v[l + 0], h1v[l + 0]};
                vf2 m1 = {h1v[l + 1], h1v[l + 1]};
                vf2 m2 = {h1v[l + 2], h1v[l + 2]};
                vf2 m3 = {h1v[l + 3], h1v[l + 3]};
                a0 = __builtin_elementwise_fma(m0, *(const vf2*)&W2[(l + 0) * 32 + h2], a0);
                a1 = __builtin_elementwise_fma(m1, *(const vf2*)&W2[(l + 1) * 32 + h2], a1);
                a2 = __builtin_elementwise_fma(m2, *(const vf2*)&W2[(l + 2) * 32 + h2], a2);
                a3 = __builtin_elementwise_fma(m3, *(const vf2*)&W2[(l + 3) * 32 + h2], a3);
            }
            vf2 a = (a0 + a1) + (a2 + a3);
#pragma unroll
            for (int s = 0; s < 2; ++s) {
                float av = a[s];
                float e = __expf(-av);
                float sil = __fdividef(av, 1.0f + e);
                o = fmaf(sil, W3[h2 + s], o);
            }
        }
        if (p < 30) sOut[wid][p] = o;
    }
    asm volatile("s_waitcnt lgkmcnt(0)" ::: "memory");
    __builtin_amdgcn_sched_barrier(0);

    const float scl = rfl_f(scale_p[0]);
    float Af[15];
    {
        int pidx = 0;
#pragma unroll
        for (int i = 0; i < 6; ++i) {
#pragma unroll
            for (int j = i + 1; j < 6; ++j) {
                float o_ij = sOut[wid][i * 5 + (j - 1)];
                float o_ji = sOut[wid][j * 5 + i];
                Af[pidx] = Ap[pidx] + scl * (o_ij - o_ji);
                ++pidx;
            }
        }
    }
    {
        double pfd = 0.0;
#define PFT(sgn, a, bb, c) pfd += (sgn) * ((double)Af[a] * (double)Af[bb] * (double)Af[c]);
        PFT( 1.0, 0, 9, 14) PFT(-1.0, 0, 10, 13) PFT( 1.0, 0, 11, 12)
        PFT(-1.0, 1, 6, 14) PFT( 1.0, 1, 7, 13)  PFT(-1.0, 1, 8, 12)
        PFT( 1.0, 2, 5, 14) PFT(-1.0, 2, 7, 11)  PFT( 1.0, 2, 8, 10)
        PFT(-1.0, 3, 5, 13) PFT( 1.0, 3, 6, 11)  PFT(-1.0, 3, 8, 9)
        PFT( 1.0, 4, 5, 12) PFT(-1.0, 4, 6, 10)  PFT( 1.0, 4, 7, 9)
#undef PFT
        if (lane == 0) {
            float pf = (float)pfd;
            float sg = (pf == 0.0f) ? 1.0f : ((pf > 0.0f) ? 1.0f : -1.0f);
            float t = pf * pf;
            float la = 0.5f * logf(t);
            out[b] = sg;
            out[B_TOTAL + b] = la;
        }
    }
}

extern "C" void kernel_launch(void* const* d_in, const int* in_sizes, int n_in,
                              void* d_out, int out_size, void* d_ws, size_t ws_size,
                              hipStream_t stream) {
    const float* x     = (const float*)d_in[0];
    const int*   spin  = (const int*)d_in[1];
    const float* Fud   = (const float*)d_in[2];
    const float* Fuu   = (const float*)d_in[3];
    const float* Fdd   = (const float*)d_in[4];
    const float* W1    = (const float*)d_in[5];
    const float* b1    = (const float*)d_in[6];
    const float* W2    = (const float*)d_in[7];
    const float* b2    = (const float*)d_in[8];
    const float* W3    = (const float*)d_in[9];
    const float* b3    = (const float*)d_in[10];
    const float* scale = (const float*)d_in[11];
    float* out = (float*)d_out;

    const size_t wsNeed = (size_t)B_TOTAL * 16 * sizeof(float);
    if (ws_size >= wsNeed) {
        float* wsAp = (float*)d_ws;
        hipLaunchKernelGGL(pfaffA, dim3(B_TOTAL / WPB), dim3(BLOCK_T), 0, stream,
                           x, spin, Fud, Fuu, Fdd, wsAp);
        hipLaunchKernelGGL(pfaffB, dim3(B_TOTAL / 16), dim3(512), 0, stream,
                           x, spin, W1, b1, W2, b2, W3, b3, scale, wsAp, out);
    } else {
        hipLaunchKernelGGL(pfaff6_full, dim3(B_TOTAL / WPB), dim3(BLOCK_T), 0, stream,
                           x, spin, Fud, Fuu, Fdd, W1, b1, W2, b2, W3, b3, scale, out);
    }
}

// Round 16
// 587.668 us; speedup vs baseline: 1.1336x; 1.0957x over previous
//
#include <hip/hip_runtime.h>
#include <math.h>

typedef float vf4 __attribute__((ext_vector_type(4)));
typedef float vf2 __attribute__((ext_vector_type(2)));

#define B_TOTAL 131072
#define WPB 8
#define BLOCK_T (WPB * 64)

__device__ __forceinline__ float rfl_f(float v) {
    return __int_as_float(__builtin_amdgcn_readfirstlane(__float_as_int(v)));
}

// physicists' Hermite H_m(t), m in [0,8), selected per-lane
__device__ __forceinline__ float herm_sel(float t, int m) {
    float h0 = 1.0f;
    float h1 = 2.0f * t;
    float r = (m == 0) ? h0 : h1;
#pragma unroll
    for (int d = 2; d < 8; ++d) {
        float hk = 2.0f * t * h1 - (2.0f * (float)(d - 1)) * h0;
        r = (m == d) ? hk : r;
        h0 = h1;
        h1 = hk;
    }
    return r;
}

// 1/sqrt((2^m * m!) * sqrt(pi)) in f64, same op order as host python
__device__ __forceinline__ float norm_of(int m) {
    double f = 1.0;
#pragma unroll
    for (int d = 2; d < 8; ++d) f = (d <= m) ? f * (double)d : f;
    double p2 = (double)(1 << m);
    double sp = sqrt(3.14159265358979323846);
    return (float)(1.0 / sqrt((p2 * f) * sp));
}

__device__ __forceinline__ float sel6f(const float* a, int m) {
    float r = a[0];
    r = (m == 1) ? a[1] : r;
    r = (m == 2) ? a[2] : r;
    r = (m == 3) ? a[3] : r;
    r = (m == 4) ? a[4] : r;
    r = (m == 5) ? a[5] : r;
    return r;
}

__device__ __forceinline__ int sel6i(const int* a, int m) {
    int r = a[0];
    r = (m == 1) ? a[1] : r;
    r = (m == 2) ? a[2] : r;
    r = (m == 3) ? a[3] : r;
    r = (m == 4) ? a[4] : r;
    r = (m == 5) ? a[5] : r;
    return r;
}

// ---- prep: antisymmetrize Fdd into ws[0..4095] (exact staging arithmetic) ----
extern "C" __global__ void __launch_bounds__(256)
pfaffPrep(const float* __restrict__ Fdd, float* __restrict__ ws)
{
    int idx = blockIdx.x * 256 + threadIdx.x;      // 0..4095
    int l = idx >> 6, k = idx & 63;
    int tr = k * 64 + l;
    ws[idx] = Fdd[idx] - Fdd[tr];
}

// ==================== Kernel A: Phi + bilinear + A-assembly -> wsAp[b*16+q] ====================
// LDS = Fuu_as (16KB) + chunked Phi stage (3KB) = 19.5KB -> wave-slot-limited
// 4 blocks/CU (32 waves). Fdd_as (ws) + Fud (raw) = 32KB global, L1-resident.
extern "C" __global__ void __launch_bounds__(BLOCK_T, 4)
pfaffA(const float* __restrict__ x, const int* __restrict__ spin,
       const float* __restrict__ Fud, const float* __restrict__ Fuu,
       const float* __restrict__ FddAs, float* __restrict__ wsAp)
{
    __shared__ alignas(16) float sFuu[4096];
    // per-chunk pair-interleaved Phi: sPhiC[w][ch][cl*2+h] = Phi[2ch+h] of l=16c+cl
    __shared__ alignas(16) float sPhiC[WPB][3][32];

    const int tid = threadIdx.x;

    for (int idx = tid; idx < 4096; idx += BLOCK_T) {
        int l = idx >> 6, k = idx & 63;
        int tr = k * 64 + l;
        sFuu[idx] = Fuu[idx] - Fuu[tr];
    }
    __syncthreads();
    // no block-wide barriers below: waves independent

    const int wid = tid >> 6;
    const int lane = tid & 63;
    const int b = blockIdx.x * WPB + wid;

    float u[6], v[6];
    int sp6[6];
#pragma unroll
    for (int i = 0; i < 6; ++i) {
        u[i] = rfl_f(x[b * 12 + 2 * i]);
        v[i] = rfl_f(x[b * 12 + 2 * i + 1]);
        sp6[i] = __builtin_amdgcn_readfirstlane(spin[b * 6 + i]);
    }

    const int mx = lane >> 3, my = lane & 7;
    const float nx = norm_of(mx), ny = norm_of(my);
    float Phi[6];
#pragma unroll
    for (int i = 0; i < 6; ++i) {
        float t = u[i] * u[i] + v[i] * v[i];
        float g = expf(-0.5f * t);                       // precise libm exp
        float hxn = herm_sel(u[i], mx) * nx;
        float hyn = herm_sel(v[i], my) * ny;
        Phi[i] = (hxn * hyn) * g;
    }

    // packed-f32 bilinear; Fuu from LDS, FddAs/Fud from global (L1-hot),
    // Phi broadcast via per-chunk LDS stage + ds_read_b128 (R15-proven).
    vf2 auu[3] = {{0.f,0.f},{0.f,0.f},{0.f,0.f}};
    vf2 add2[3] = {{0.f,0.f},{0.f,0.f},{0.f,0.f}};
    vf2 aud[3] = {{0.f,0.f},{0.f,0.f},{0.f,0.f}};
    const float* fdb = FddAs + lane;
    const float* fxb = Fud + lane;
    const int cl = lane & 15;
#pragma unroll 1
    for (int c = 0; c < 4; ++c) {
        // stage Phi for l in [16c, 16c+16): lanes of this chunk write theirs.
        asm volatile("s_waitcnt lgkmcnt(0)" ::: "memory");
        __builtin_amdgcn_sched_barrier(0);
        if ((lane >> 4) == c) {
#pragma unroll
            for (int i = 0; i < 6; ++i)
                sPhiC[wid][i >> 1][cl * 2 + (i & 1)] = Phi[i];
        }
        asm volatile("s_waitcnt lgkmcnt(0)" ::: "memory");
        __builtin_amdgcn_sched_barrier(0);

#pragma unroll
        for (int l2 = 0; l2 < 16; l2 += 2) {
            const int l = c * 16 + l2;
            vf4 pq0 = *(const vf4*)&sPhiC[wid][0][l2 * 2];
            vf4 pq1 = *(const vf4*)&sPhiC[wid][1][l2 * 2];
            vf4 pq2 = *(const vf4*)&sPhiC[wid][2][l2 * 2];
#pragma unroll
            for (int d = 0; d < 2; ++d) {
                float fu = sFuu[(l + d) * 64 + lane];
                float fd = fdb[(l2 + d) * 64];
                float fx = fxb[(l2 + d) * 64];
                vf2 fu2 = {fu, fu}, fd2 = {fd, fd}, fx2 = {fx, fx};
                vf2 p0 = {pq0[2 * d], pq0[2 * d + 1]};
                vf2 p1 = {pq1[2 * d], pq1[2 * d + 1]};
                vf2 p2 = {pq2[2 * d], pq2[2 * d + 1]};
                auu[0] = __builtin_elementwise_fma(p0, fu2, auu[0]);
                auu[1] = __builtin_elementwise_fma(p1, fu2, auu[1]);
                auu[2] = __builtin_elementwise_fma(p2, fu2, auu[2]);
                add2[0] = __builtin_elementwise_fma(p0, fd2, add2[0]);
                add2[1] = __builtin_elementwise_fma(p1, fd2, add2[1]);
                add2[2] = __builtin_elementwise_fma(p2, fd2, add2[2]);
                aud[0] = __builtin_elementwise_fma(p0, fx2, aud[0]);
                aud[1] = __builtin_elementwise_fma(p1, fx2, aud[1]);
                aud[2] = __builtin_elementwise_fma(p2, fx2, aud[2]);
            }
        }
        fdb += 1024;
        fxb += 1024;
    }
    float puu[6], pdd[6], pud[6];
#pragma unroll
    for (int c = 0; c < 3; ++c) {
        puu[2 * c] = auu[c][0];  puu[2 * c + 1] = auu[c][1];
        pdd[2 * c] = add2[c][0]; pdd[2 * c + 1] = add2[c][1];
        pud[2 * c] = aud[c][0];  pud[2 * c + 1] = aud[c][1];
    }

    // A[i<j]: spin-selected bilinear forms, butterfly reduce; lane pidx keeps its value
    float myAp = 0.0f;
    {
        int pidx = 0;
#pragma unroll
        for (int i = 0; i < 6; ++i) {
#pragma unroll
            for (int j = i + 1; j < 6; ++j) {
                int si = sp6[i], sj = sp6[j];
                bool du = (si == 1) && (sj == 0);
                float rowv = (si == 0) ? ((sj == 0) ? puu[i] : pud[i])
                                       : ((sj == 1) ? pdd[i] : pud[j]);
                float colv = du ? Phi[i] : Phi[j];
                float prod = rowv * colv;
                prod = du ? -prod : prod;
#pragma unroll
                for (int m = 32; m >= 1; m >>= 1)
                    prod += __shfl_xor(prod, m, 64);
                myAp = (lane == pidx) ? prod : myAp;
                ++pidx;
            }
        }
    }
    if (lane < 15) wsAp[b * 16 + lane] = myAp;
}

// ==================== Kernel B: per-pair MLP + Pfaffian ====================
// thread = one ordered pair (p<30) of one element; 32 threads (half-wave) per element.
extern "C" __global__ void __launch_bounds__(512, 6)
pfaffB(const float* __restrict__ x, const int* __restrict__ spin,
       const float* __restrict__ W1, const float* __restrict__ b1,
       const float* __restrict__ W2, const float* __restrict__ b2,
       const float* __restrict__ W3, const float* __restrict__ b3,
       const float* __restrict__ scale_p, const float* __restrict__ wsAp,
       float* __restrict__ out)
{
    const int tid = threadIdx.x;
    const int half = tid >> 5;
    const int p = tid & 31;
    const int b = blockIdx.x * 16 + half;

    int i = p / 5;
    int r5 = p - i * 5;
    int j = r5 + ((r5 >= i) ? 1 : 0);
    i = min(i, 5);
    j = min(j, 5);

    float xi = x[b * 12 + 2 * i], yi = x[b * 12 + 2 * i + 1];
    float xj = x[b * 12 + 2 * j], yj = x[b * 12 + 2 * j + 1];
    int si = spin[b * 6 + i], sj = spin[b * 6 + j];

    float dx = xi - xj;
    float dy = yi - yj;
    float r2 = dx * dx + dy * dy;
    float same = (si == sj) ? 1.0f : 0.0f;
    vf2 dx2 = {dx, dx}, dy2 = {dy, dy}, r22 = {r2, r2}, sm2 = {same, same};

    // pk-MLP (R9's exact arithmetic); weight addresses wave-uniform -> s_load
    float h1v[32];
#pragma unroll
    for (int h = 0; h < 32; h += 2) {
        vf2 a = *(const vf2*)&b1[h];
        a = __builtin_elementwise_fma(dx2, *(const vf2*)&W1[h], a);
        a = __builtin_elementwise_fma(dy2, *(const vf2*)&W1[32 + h], a);
        a = __builtin_elementwise_fma(r22, *(const vf2*)&W1[64 + h], a);
        a = __builtin_elementwise_fma(sm2, *(const vf2*)&W1[96 + h], a);
#pragma unroll
        for (int s = 0; s < 2; ++s) {
            float av = a[s];
            float e = __expf(-av);
            h1v[h + s] = __fdividef(av, 1.0f + e);   // silu
        }
    }
    float o = b3[0];
    for (int h2 = 0; h2 < 32; h2 += 2) {
        vf2 a0 = *(const vf2*)&b2[h2];
        vf2 a1 = {0.f, 0.f}, a2 = {0.f, 0.f}, a3 = {0.f, 0.f};
#pragma unroll
        for (int l = 0; l < 32; l += 4) {
            vf2 m0 = {h1v[l + 0], h1v[l + 0]};
            vf2 m1 = {h1v[l + 1], h1v[l + 1]};
            vf2 m2 = {h1v[l + 2], h1v[l + 2]};
            vf2 m3 = {h1v[l + 3], h1v[l + 3]};
            a0 = __builtin_elementwise_fma(m0, *(const vf2*)&W2[(l + 0) * 32 + h2], a0);
            a1 = __builtin_elementwise_fma(m1, *(const vf2*)&W2[(l + 1) * 32 + h2], a1);
            a2 = __builtin_elementwise_fma(m2, *(const vf2*)&W2[(l + 2) * 32 + h2], a2);
            a3 = __builtin_elementwise_fma(m3, *(const vf2*)&W2[(l + 3) * 32 + h2], a3);
        }
        vf2 a = (a0 + a1) + (a2 + a3);
#pragma unroll
        for (int s = 0; s < 2; ++s) {
            float av = a[s];
            float e = __expf(-av);
            float sil = __fdividef(av, 1.0f + e);    // silu
            o = fmaf(sil, W3[h2 + s], o);
        }
    }

    // ---- Af assembly at lanes q<15 of each half-wave ----
    const int t = p & 15;
    const unsigned long long TI = 0x0433222111100000ull;
    const unsigned long long TJ = 0x0554543543254321ull;
    int i2 = (int)((TI >> (4 * t)) & 15);
    int j2 = (int)((TJ >> (4 * t)) & 15);
    float o_ij = __shfl(o, i2 * 5 + (j2 - 1), 32);   // ord(i2,j2), j2>i2
    float o_ji = __shfl(o, j2 * 5 + i2, 32);         // ord(j2,i2)
    const float scl = scale_p[0];
    float ApV = wsAp[b * 16 + t];
    float Af = ApV + scl * (o_ij - o_ji);

    // ---- Pfaffian: lane t<15 computes term t, f64 tree-sum across half ----
    const unsigned long long TA = 0x0444333222111000ull;
    const unsigned long long TB = 0x0765865875876BA9ull;
    const unsigned long long TC = 0x09AC9BDABECDECDEull;
    int ia = (int)((TA >> (4 * t)) & 15);
    int ib = (int)((TB >> (4 * t)) & 15);
    int ic = (int)((TC >> (4 * t)) & 15);
    double Afa = (double)__shfl(Af, ia, 32);
    double Afb = (double)__shfl(Af, ib, 32);
    double Afc = (double)__shfl(Af, ic, 32);
    double pd = Afa * Afb * Afc;
    pd = (t & 1) ? -pd : pd;
    pd = (p < 15) ? pd : 0.0;
#pragma unroll
    for (int m = 16; m >= 1; m >>= 1)
        pd += __shfl_xor(pd, m, 32);

    if (p == 0) {
        float pf = (float)pd;
        float sg = (pf == 0.0f) ? 1.0f : ((pf > 0.0f) ? 1.0f : -1.0f);
        float tt = pf * pf;                // ref adds 1e-60 which is 0 in f32
        float la = 0.5f * logf(tt);
        out[b] = sg;
        out[B_TOTAL + b] = la;
    }
}

// ==================== fallback (ws too small): R9 fused kernel ====================
extern "C" __global__ void __launch_bounds__(BLOCK_T, 4)
pfaff6_full(const float* __restrict__ x, const int* __restrict__ spin,
            const float* __restrict__ Fud, const float* __restrict__ Fuu,
            const float* __restrict__ Fdd,
            const float* __restrict__ W1, const float* __restrict__ b1,
            const float* __restrict__ W2, const float* __restrict__ b2,
            const float* __restrict__ W3, const float* __restrict__ b3,
            const float* __restrict__ scale_p,
            float* __restrict__ out)
{
    __shared__ alignas(16) float sFuu[4096];
    __shared__ alignas(16) float sFdd[4096];
    __shared__ alignas(16) float sFud[4096];
    __shared__ alignas(16) float sPhi2[WPB][3][128];
    __shared__ float sOut[WPB][32];

    const int tid = threadIdx.x;
    for (int idx = tid; idx < 4096; idx += BLOCK_T) {
        int l = idx >> 6, k = idx & 63;
        int tr = k * 64 + l;
        sFuu[idx] = Fuu[idx] - Fuu[tr];
        sFdd[idx] = Fdd[idx] - Fdd[tr];
        sFud[idx] = Fud[idx];
    }
    __syncthreads();

    const int wid = tid >> 6;
    const int lane = tid & 63;
    const int b = blockIdx.x * WPB + wid;

    float u[6], v[6];
    int sp6[6];
#pragma unroll
    for (int i = 0; i < 6; ++i) {
        u[i] = rfl_f(x[b * 12 + 2 * i]);
        v[i] = rfl_f(x[b * 12 + 2 * i + 1]);
        sp6[i] = __builtin_amdgcn_readfirstlane(spin[b * 6 + i]);
    }

    const int mx = lane >> 3, my = lane & 7;
    const float nx = norm_of(mx), ny = norm_of(my);
    float Phi[6];
#pragma unroll
    for (int i = 0; i < 6; ++i) {
        float t = u[i] * u[i] + v[i] * v[i];
        float g = expf(-0.5f * t);
        float ph = ((herm_sel(u[i], mx) * nx) * (herm_sel(v[i], my) * ny)) * g;
        Phi[i] = ph;
        sPhi2[wid][i >> 1][lane * 2 + (i & 1)] = ph;
    }
    asm volatile("s_waitcnt lgkmcnt(0)" ::: "memory");
    __builtin_amdgcn_sched_barrier(0);

    vf2 auu[3] = {{0.f,0.f},{0.f,0.f},{0.f,0.f}};
    vf2 add2[3] = {{0.f,0.f},{0.f,0.f},{0.f,0.f}};
    vf2 aud[3] = {{0.f,0.f},{0.f,0.f},{0.f,0.f}};
    for (int l2 = 0; l2 < 64; l2 += 2) {
        vf4 pq0 = *(const vf4*)&sPhi2[wid][0][l2 * 2];
        vf4 pq1 = *(const vf4*)&sPhi2[wid][1][l2 * 2];
        vf4 pq2 = *(const vf4*)&sPhi2[wid][2][l2 * 2];
#pragma unroll
        for (int d = 0; d < 2; ++d) {
            int l = l2 + d;
            float fu = sFuu[l * 64 + lane];
            float fd = sFdd[l * 64 + lane];
            float fx = sFud[l * 64 + lane];
            vf2 fu2 = {fu, fu}, fd2 = {fd, fd}, fx2 = {fx, fx};
            vf2 p0 = {pq0[2 * d], pq0[2 * d + 1]};
            vf2 p1 = {pq1[2 * d], pq1[2 * d + 1]};
            vf2 p2 = {pq2[2 * d], pq2[2 * d + 1]};
            auu[0] = __builtin_elementwise_fma(p0, fu2, auu[0]);
            auu[1] = __builtin_elementwise_fma(p1, fu2, auu[1]);
            auu[2] = __builtin_elementwise_fma(p2, fu2, auu[2]);
            add2[0] = __builtin_elementwise_fma(p0, fd2, add2[0]);
            add2[1] = __builtin_elementwise_fma(p1, fd2, add2[1]);
            add2[2] = __builtin_elementwise_fma(p2, fd2, add2[2]);
            aud[0] = __builtin_elementwise_fma(p0, fx2, aud[0]);
            aud[1] = __builtin_elementwise_fma(p1, fx2, aud[1]);
            aud[2] = __builtin_elementwise_fma(p2, fx2, aud[2]);
        }
    }
    float puu[6], pdd[6], pud[6];
#pragma unroll
    for (int c = 0; c < 3; ++c) {
        puu[2 * c] = auu[c][0];  puu[2 * c + 1] = auu[c][1];
        pdd[2 * c] = add2[c][0]; pdd[2 * c + 1] = add2[c][1];
        pud[2 * c] = aud[c][0];  pud[2 * c + 1] = aud[c][1];
    }

    float Ap[15];
    {
        int pidx = 0;
#pragma unroll
        for (int i = 0; i < 6; ++i) {
#pragma unroll
            for (int j = i + 1; j < 6; ++j) {
                int si = sp6[i], sj = sp6[j];
                bool du = (si == 1) && (sj == 0);
                float rowv = (si == 0) ? ((sj == 0) ? puu[i] : pud[i])
                                       : ((sj == 1) ? pdd[i] : pud[j]);
                float colv = du ? Phi[i] : Phi[j];
                float prod = rowv * colv;
                prod = du ? -prod : prod;
#pragma unroll
                for (int m = 32; m >= 1; m >>= 1)
                    prod += __shfl_xor(prod, m, 64);
                Ap[pidx++] = rfl_f(prod);
            }
        }
    }

    {
        int p = lane;
        int i = p / 5;
        int r5 = p - i * 5;
        int j = r5 + ((r5 >= i) ? 1 : 0);
        i = min(i, 5);
        j = min(j, 5);
        float dx = sel6f(u, i) - sel6f(u, j);
        float dy = sel6f(v, i) - sel6f(v, j);
        float r2 = dx * dx + dy * dy;
        float same = (sel6i(sp6, i) == sel6i(sp6, j)) ? 1.0f : 0.0f;
        vf2 dx2 = {dx, dx}, dy2 = {dy, dy}, r22 = {r2, r2}, sm2 = {same, same};

        float h1v[32];
#pragma unroll
        for (int h = 0; h < 32; h += 2) {
            vf2 a = *(const vf2*)&b1[h];
            a = __builtin_elementwise_fma(dx2, *(const vf2*)&W1[h], a);
            a = __builtin_elementwise_fma(dy2, *(const vf2*)&W1[32 + h], a);
            a = __builtin_elementwise_fma(r22, *(const vf2*)&W1[64 + h], a);
            a = __builtin_elementwise_fma(sm2, *(const vf2*)&W1[96 + h], a);
#pragma unroll
            for (int s = 0; s < 2; ++s) {
                float av = a[s];
                float e = __expf(-av);
                h1v[h + s] = __fdividef(av, 1.0f + e);
            }
        }
        float o = b3[0];
        for (int h2 = 0; h2 < 32; h2 += 2) {
            vf2 a0 = *(const vf2*)&b2[h2];
            vf2 a1 = {0.f, 0.f}, a2 = {0.f, 0.f}, a3 = {0.f, 0.f};
#pragma unroll
            for (int l = 0; l < 32; l += 4) {
                vf2 m0 = {h1v[l + 0], h1v[l + 0]};
                vf2 m1 = {h1v[l + 1], h1v[l + 1]};
                vf2 m2 = {h1v[l + 2], h1v[l + 2]};
                vf2 m3 = {h1v[l + 3], h1v[l + 3]};
                a0 = __builtin_elementwise_fma(m0, *(const vf2*)&W2[(l + 0) * 32 + h2], a0);
                a1 = __builtin_elementwise_fma(m1, *(const vf2*)&W2[(l + 1) * 32 + h2], a1);
                a2 = __builtin_elementwise_fma(m2, *(const vf2*)&W2[(l + 2) * 32 + h2], a2);
                a3 = __builtin_elementwise_fma(m3, *(const vf2*)&W2[(l + 3) * 32 + h2], a3);
            }
            vf2 a = (a0 + a1) + (a2 + a3);
#pragma unroll
            for (int s = 0; s < 2; ++s) {
                float av = a[s];
                float e = __expf(-av);
                float sil = __fdividef(av, 1.0f + e);
                o = fmaf(sil, W3[h2 + s], o);
            }
        }
        if (p < 30) sOut[wid][p] = o;
    }
    asm volatile("s_waitcnt lgkmcnt(0)" ::: "memory");
    __builtin_amdgcn_sched_barrier(0);

    const float scl = rfl_f(scale_p[0]);
    float Af[15];
    {
        int pidx = 0;
#pragma unroll
        for (int i = 0; i < 6; ++i) {
#pragma unroll
            for (int j = i + 1; j < 6; ++j) {
                float o_ij = sOut[wid][i * 5 + (j - 1)];
                float o_ji = sOut[wid][j * 5 + i];
                Af[pidx] = Ap[pidx] + scl * (o_ij - o_ji);
                ++pidx;
            }
        }
    }
    {
        double pfd = 0.0;
#define PFT(sgn, a, bb, c) pfd += (sgn) * ((double)Af[a] * (double)Af[bb] * (double)Af[c]);
        PFT( 1.0, 0, 9, 14) PFT(-1.0, 0, 10, 13) PFT( 1.0, 0, 11, 12)
        PFT(-1.0, 1, 6, 14) PFT( 1.0, 1, 7, 13)  PFT(-1.0, 1, 8, 12)
        PFT( 1.0, 2, 5, 14) PFT(-1.0, 2, 7, 11)  PFT( 1.0, 2, 8, 10)
        PFT(-1.0, 3, 5, 13) PFT( 1.0, 3, 6, 11)  PFT(-1.0, 3, 8, 9)
        PFT( 1.0, 4, 5, 12) PFT(-1.0, 4, 6, 10)  PFT( 1.0, 4, 7, 9)
#undef PFT
        if (lane == 0) {
            float pf = (float)pfd;
            float sg = (pf == 0.0f) ? 1.0f : ((pf > 0.0f) ? 1.0f : -1.0f);
            float t = pf * pf;
            float la = 0.5f * logf(t);
            out[b] = sg;
            out[B_TOTAL + b] = la;
        }
    }
}

extern "C" void kernel_launch(void* const* d_in, const int* in_sizes, int n_in,
                              void* d_out, int out_size, void* d_ws, size_t ws_size,
                              hipStream_t stream) {
    const float* x     = (const float*)d_in[0];
    const int*   spin  = (const int*)d_in[1];
    const float* Fud   = (const float*)d_in[2];
    const float* Fuu   = (const float*)d_in[3];
    const float* Fdd   = (const float*)d_in[4];
    const float* W1    = (const float*)d_in[5];
    const float* b1    = (const float*)d_in[6];
    const float* W2    = (const float*)d_in[7];
    const float* b2    = (const float*)d_in[8];
    const float* W3    = (const float*)d_in[9];
    const float* b3    = (const float*)d_in[10];
    const float* scale = (const float*)d_in[11];
    float* out = (float*)d_out;

    const size_t wsNeed = (size_t)(4096 + B_TOTAL * 16) * sizeof(float);
    if (ws_size >= wsNeed) {
        float* FddAs = (float*)d_ws;
        float* wsAp  = FddAs + 4096;
        hipLaunchKernelGGL(pfaffPrep, dim3(16), dim3(256), 0, stream, Fdd, FddAs);
        hipLaunchKernelGGL(pfaffA, dim3(B_TOTAL / WPB), dim3(BLOCK_T), 0, stream,
                           x, spin, Fud, Fuu, FddAs, wsAp);
        hipLaunchKernelGGL(pfaffB, dim3(B_TOTAL / 16), dim3(512), 0, stream,
                           x, spin, W1, b1, W2, b2, W3, b3, scale, wsAp, out);
    } else {
        hipLaunchKernelGGL(pfaff6_full, dim3(B_TOTAL / WPB), dim3(BLOCK_T), 0, stream,
                           x, spin, Fud, Fuu, Fdd, W1, b1, W2, b2, W3, b3, scale, out);
    }
}